// Round 14
// baseline (177.427 us; speedup 1.0000x reference)
//
#include <hip/hip_runtime.h>
#include <hip/hip_bf16.h>
#include <math.h>

// Problem constants
#define B_   8
#define Q_   300
#define C_   256
#define NH_  8
#define NL_  4
#define NP_  4
#define DFF_ 1024
#define DH_  32
#define LEN_ 13294
#define MQ_  (B_*Q_)    // 2400
#define MV_  (B_*LEN_)  // 106352

typedef __attribute__((ext_vector_type(4))) float f32x4;
typedef __attribute__((ext_vector_type(8))) short bf16x8;
typedef __hip_bfloat16 bf16;

#define GLOAD16(gp, lp) __builtin_amdgcn_global_load_lds( \
    (const __attribute__((address_space(1))) unsigned int*)(gp), \
    (__attribute__((address_space(3))) unsigned int*)(lp), 16, 0, 0)

// bit-preserving float -> bf16 bits (avoid short->bf16 numeric-conversion trap)
__device__ __forceinline__ short f2bfbits(float x) {
    bf16 h = __float2bfloat16(x);
    return *reinterpret_cast<short*>(&h);
}

// ---------------- dual convert: qk_bf = bf16(tgt+qpe), tgt_bf = bf16(tgt) ----------------
__global__ __launch_bounds__(256) void k_dualcvt(const float* __restrict__ tgt,
                                                 const float* __restrict__ qpe,
                                                 bf16* __restrict__ qk_o,
                                                 bf16* __restrict__ tgt_o, int n8) {
    int i = blockIdx.x * 256 + threadIdx.x;
    if (i >= n8) return;
    const float4* pa = (const float4*)(tgt + (size_t)i * 8);
    const float4* pb = (const float4*)(qpe + (size_t)i * 8);
    float4 x = pa[0], y = pa[1], u = pb[0], w = pb[1];
    union { bf16 h[8]; uint4 v; } s, t;
    s.h[0] = __float2bfloat16(x.x + u.x); s.h[1] = __float2bfloat16(x.y + u.y);
    s.h[2] = __float2bfloat16(x.z + u.z); s.h[3] = __float2bfloat16(x.w + u.w);
    s.h[4] = __float2bfloat16(y.x + w.x); s.h[5] = __float2bfloat16(y.y + w.y);
    s.h[6] = __float2bfloat16(y.z + w.z); s.h[7] = __float2bfloat16(y.w + w.w);
    t.h[0] = __float2bfloat16(x.x); t.h[1] = __float2bfloat16(x.y);
    t.h[2] = __float2bfloat16(x.z); t.h[3] = __float2bfloat16(x.w);
    t.h[4] = __float2bfloat16(y.x); t.h[5] = __float2bfloat16(y.y);
    t.h[6] = __float2bfloat16(y.z); t.h[7] = __float2bfloat16(y.w);
    *(uint4*)(qk_o + (size_t)i * 8)  = s.v;
    *(uint4*)(tgt_o + (size_t)i * 8) = t.v;
}

// ---------------- all weight transposes in one launch ----------------
__global__ __launch_bounds__(256) void k_wtall(
        const float* __restrict__ Wq, const float* __restrict__ Wk,
        const float* __restrict__ Wv, const float* __restrict__ Wo,
        const float* __restrict__ Wval, const float* __restrict__ Woff,
        const float* __restrict__ Wattn, const float* __restrict__ Wout,
        const float* __restrict__ W1, const float* __restrict__ W2,
        bf16* __restrict__ Wqk_t, bf16* __restrict__ Wv_t, bf16* __restrict__ Wo_t,
        bf16* __restrict__ Wval_t, bf16* __restrict__ Woa_t, bf16* __restrict__ Wout_t,
        bf16* __restrict__ W1_t, bf16* __restrict__ W2_t) {
    __shared__ float t[32][33];
    const int id = blockIdx.x;
    const float* W; bf16* D; int K, N, r;
    if      (id < 64)  { W = Wq;    D = Wqk_t;          K = 256;  N = 256;  r = id; }
    else if (id < 128) { W = Wk;    D = Wqk_t + 65536;  K = 256;  N = 256;  r = id - 64; }
    else if (id < 192) { W = Wv;    D = Wv_t;           K = 256;  N = 256;  r = id - 128; }
    else if (id < 256) { W = Wo;    D = Wo_t;           K = 256;  N = 256;  r = id - 192; }
    else if (id < 320) { W = Wval;  D = Wval_t;         K = 256;  N = 256;  r = id - 256; }
    else if (id < 384) { W = Woff;  D = Woa_t;          K = 256;  N = 256;  r = id - 320; }
    else if (id < 416) { W = Wattn; D = Woa_t + 65536;  K = 256;  N = 128;  r = id - 384; }
    else if (id < 480) { W = Wout;  D = Wout_t;         K = 256;  N = 256;  r = id - 416; }
    else if (id < 736) { W = W1;    D = W1_t;           K = 256;  N = 1024; r = id - 480; }
    else               { W = W2;    D = W2_t;           K = 1024; N = 256;  r = id - 736; }
    const int nx = N >> 5;
    const int k0 = (r / nx) * 32, n0 = (r % nx) * 32;
    const int c = threadIdx.x & 31, rr = threadIdx.x >> 5;
#pragma unroll
    for (int i = 0; i < 4; ++i)
        t[rr + i * 8][c] = W[(size_t)(k0 + rr + i * 8) * N + n0 + c];
    __syncthreads();
#pragma unroll
    for (int i = 0; i < 4; ++i)
        D[(size_t)(n0 + rr + i * 8) * K + k0 + c] = __float2bfloat16(t[c][rr + i * 8]);
}

// ---------------- 64x64 MFMA GEMM (high occupancy, dual bias) ----------------
template<int RELU, int OUT_MODE>
__global__ __launch_bounds__(256) void k_gmm64(const bf16* __restrict__ A,
                                               const bf16* __restrict__ Bt,
                                               const float* __restrict__ bias0,
                                               const float* __restrict__ bias1,
                                               int nsplit,
                                               float* __restrict__ outf,
                                               bf16* __restrict__ outh,
                                               int M, int N, int K) {
    __shared__ bf16 As[64 * 32];
    __shared__ bf16 Bs[64 * 32];
    const int tid  = threadIdx.x;
    const int wid  = tid >> 6, lane = tid & 63;
    const int m0 = blockIdx.y * 64, n0 = blockIdx.x * 64;
    const int wr = wid >> 1, wc = wid & 1;       // 2x2 waves of 32x32
    const int fr = lane & 15, fq = lane >> 4;
    const int rloc = wid * 16 + (lane >> 2);
    const int kof  = (lane & 3) * 8;
    f32x4 acc[2][2] = {};
    for (int k0 = 0; k0 < K; k0 += 32) {
        if (k0) __syncthreads();
        int gr = m0 + rloc; if (gr > M - 1) gr = M - 1;
        GLOAD16(A + (size_t)gr * K + k0 + kof, As + rloc * 32);
        int gc = n0 + rloc; if (gc > N - 1) gc = N - 1;
        GLOAD16(Bt + (size_t)gc * K + k0 + kof, Bs + rloc * 32);
        __syncthreads();
        bf16x8 af[2], bfr[2];
#pragma unroll
        for (int m = 0; m < 2; ++m)
            af[m] = *(const bf16x8*)(As + (wr * 32 + m * 16 + fr) * 32 + fq * 8);
#pragma unroll
        for (int n = 0; n < 2; ++n)
            bfr[n] = *(const bf16x8*)(Bs + (wc * 32 + n * 16 + fr) * 32 + fq * 8);
#pragma unroll
        for (int m = 0; m < 2; ++m)
#pragma unroll
            for (int n = 0; n < 2; ++n)
                acc[m][n] = __builtin_amdgcn_mfma_f32_16x16x32_bf16(af[m], bfr[n], acc[m][n], 0, 0, 0);
    }
#pragma unroll
    for (int m = 0; m < 2; ++m) {
#pragma unroll
        for (int n = 0; n < 2; ++n) {
            const int c = n0 + wc * 32 + n * 16 + fr;
            const float bs = (c < nsplit) ? bias0[c] : bias1[c - nsplit];
#pragma unroll
            for (int j = 0; j < 4; ++j) {
                const int r = m0 + wr * 32 + m * 16 + fq * 4 + j;
                if (r >= M) continue;
                float v = acc[m][n][j] + bs;
                if (RELU) v = fmaxf(v, 0.f);
                if (OUT_MODE == 0) outf[(size_t)r * N + c] = v;
                else               outh[(size_t)r * N + c] = __float2bfloat16(v);
            }
        }
    }
}

// ---------------- fused self-attention: QK^T -> softmax -> PV ----------------
__global__ __launch_bounds__(256) void k_attn(const bf16* __restrict__ qk2,
                                              const bf16* __restrict__ vb,
                                              bf16* __restrict__ sa) {
    __shared__ short Ks[304][40];       // [key][d], stride 40 => conflict-free frag reads
    __shared__ short Vt[32][328];       // [d][key] transposed
    __shared__ short Ps[4][16][168];    // per-wave P half-tile [qrow][key_local]
    const int tid = threadIdx.x, w = tid >> 6, lane = tid & 63;
    const int fr = lane & 15, fq = lane >> 4;
    const int bh = blockIdx.y, b = bh >> 3, h = bh & 7;
    const int qbase = blockIdx.x * 64;

    // stage K rows and transposed V
    for (int k0 = 0; k0 < 300; k0 += 64) {
        int key = k0 + (tid >> 2);
        int dc = (tid & 3) * 8;
        if (key < 300) {
            *(bf16x8*)&Ks[key][dc] =
                *(const bf16x8*)&qk2[((size_t)(b * 300 + key)) * 512 + 256 + h * 32 + dc];
            bf16x8 v8 = *(const bf16x8*)&vb[((size_t)(b * 300 + key)) * 256 + h * 32 + dc];
#pragma unroll
            for (int i = 0; i < 8; ++i) Vt[dc + i][key] = v8[i];   // short = short: bit copy
        }
    }
    for (int i = tid; i < 32 * 20; i += 256) Vt[i & 31][300 + (i >> 5)] = 0;

    // Q A-fragment straight from global
    int qrow = qbase + w * 16 + fr;
    int qr = qrow < 300 ? qrow : 299;
    bf16x8 qf = *(const bf16x8*)&qk2[((size_t)(b * 300 + qr)) * 512 + h * 32 + fq * 8];
    __syncthreads();

    // S = Q K^T (19 key tiles of 16)
    f32x4 s[19];
#pragma unroll
    for (int kf = 0; kf < 19; ++kf) {
        bf16x8 kfr = *(const bf16x8*)&Ks[kf * 16 + fr][fq * 8];
        f32x4 z = {};
        s[kf] = __builtin_amdgcn_mfma_f32_16x16x32_bf16(qf, kfr, z, 0, 0, 0);
    }
    const float scale = 0.17677669529663687f;
#pragma unroll
    for (int kf = 0; kf < 19; ++kf)
#pragma unroll
        for (int j = 0; j < 4; ++j) s[kf][j] *= scale;
    if (288 + fr >= 300) {
#pragma unroll
        for (int j = 0; j < 4; ++j) s[18][j] = -1e30f;
    }
    float mx[4], sm[4], inv[4];
#pragma unroll
    for (int j = 0; j < 4; ++j) {
        mx[j] = s[0][j];
#pragma unroll
        for (int kf = 1; kf < 19; ++kf) mx[j] = fmaxf(mx[j], s[kf][j]);
    }
#pragma unroll
    for (int off = 1; off < 16; off <<= 1)
#pragma unroll
        for (int j = 0; j < 4; ++j) mx[j] = fmaxf(mx[j], __shfl_xor(mx[j], off));
#pragma unroll
    for (int j = 0; j < 4; ++j) sm[j] = 0.f;
#pragma unroll
    for (int kf = 0; kf < 19; ++kf)
#pragma unroll
        for (int j = 0; j < 4; ++j) { s[kf][j] = expf(s[kf][j] - mx[j]); sm[j] += s[kf][j]; }
#pragma unroll
    for (int off = 1; off < 16; off <<= 1)
#pragma unroll
        for (int j = 0; j < 4; ++j) sm[j] += __shfl_xor(sm[j], off);
#pragma unroll
    for (int j = 0; j < 4; ++j) inv[j] = 1.f / sm[j];

    // PV in two key-halves (Ps per-wave private; wave-synchronous LDS, DS in-order per wave)
    f32x4 o[2] = {};
#pragma unroll
    for (int half = 0; half < 2; ++half) {
        const int kfbeg = half * 10, kfend = half ? 19 : 10;
#pragma unroll
        for (int kf = kfbeg; kf < kfend; ++kf) {
            int gcol = kf * 16 + fr, lcol = gcol - half * 160;
            bool valid = gcol < 300;
#pragma unroll
            for (int j = 0; j < 4; ++j)
                Ps[w][fq * 4 + j][lcol] = valid ? f2bfbits(s[kf][j] * inv[j]) : (short)0;
        }
        if (half) {  // zero local cols 144..159 (global 304..319)
            int r = lane >> 2, c0 = 144 + (lane & 3) * 4;
#pragma unroll
            for (int i = 0; i < 4; ++i) Ps[w][r][c0 + i] = 0;
        }
#pragma unroll
        for (int ks = 0; ks < 5; ++ks) {
            bf16x8 pa = *(const bf16x8*)&Ps[w][fr][ks * 32 + fq * 8];
#pragma unroll
            for (int n = 0; n < 2; ++n) {
                bf16x8 vf = *(const bf16x8*)&Vt[n * 16 + fr][half * 160 + ks * 32 + fq * 8];
                o[n] = __builtin_amdgcn_mfma_f32_16x16x32_bf16(pa, vf, o[n], 0, 0, 0);
            }
        }
    }
#pragma unroll
    for (int n = 0; n < 2; ++n)
#pragma unroll
        for (int j = 0; j < 4; ++j) {
            int row = qbase + w * 16 + fq * 4 + j;
            if (row < 300)
                sa[((size_t)(b * 300 + row)) * 256 + h * 32 + n * 16 + fr] = __float2bfloat16(o[n][j]);
        }
}

// ---------------- LayerNorm(x + res); WB=1: outh=bf16(y); WB=2: outh=bf16(y+qpe) ----------------
template<int WB>
__global__ __launch_bounds__(256) void k_ln(const float* __restrict__ x,
                                            const float* __restrict__ res,
                                            const float* __restrict__ qpe,
                                            const float* __restrict__ g,
                                            const float* __restrict__ be,
                                            float* __restrict__ out,
                                            bf16* __restrict__ outh, int rows) {
    const int row = blockIdx.x;
    const int tid = threadIdx.x;
    float v = x[row * C_ + tid] + res[row * C_ + tid];
    __shared__ float red[4];
    float s = v;
#pragma unroll
    for (int off = 32; off; off >>= 1) s += __shfl_xor(s, off);
    if ((tid & 63) == 0) red[tid >> 6] = s;
    __syncthreads();
    float mean = (red[0] + red[1] + red[2] + red[3]) * (1.f / C_);
    float dv = v - mean;
    float s2 = dv * dv;
    __syncthreads();
#pragma unroll
    for (int off = 32; off; off >>= 1) s2 += __shfl_xor(s2, off);
    if ((tid & 63) == 0) red[tid >> 6] = s2;
    __syncthreads();
    float var = (red[0] + red[1] + red[2] + red[3]) * (1.f / C_);
    float rstd = 1.f / sqrtf(var + 1e-5f);
    float y = dv * rstd * g[tid] + be[tid];
    out[row * C_ + tid] = y;
    if (WB == 1) outh[row * C_ + tid] = __float2bfloat16(y);
    if (WB == 2) outh[row * C_ + tid] = __float2bfloat16(y + qpe[row * C_ + tid]);
}

// ---------------- deformable sampling on RAW memory (linearity rewrite) ----------------
// agg[bq*8+h][256] = sum_{l,p,corner} aw * w_c * memory[b, pix, 0:256]  (fp32)
// wsumb[bq*8+h]    = sum aw * w_c   (for the deferred bias term)
// One wave per (b,q,h); each lane owns 4 channels -> every corner read is one
// fully-coalesced 1KB row (64 lanes x float4). Softmax over the 16 aw logits fused.
__global__ __launch_bounds__(256) void k_sampleraw(const float* __restrict__ memory,
                                                   const float* __restrict__ refp,
                                                   const float* __restrict__ offaw,
                                                   float* __restrict__ agg,
                                                   float* __restrict__ wsumb) {
    const int w = threadIdx.x >> 6, lane = threadIdx.x & 63;
    const int g = blockIdx.x * 4 + w;        // (bq*8 + h), 0..19199
    const int h = g & 7, bq = g >> 3, b = bq / Q_;
    const int starts[4] = {0, 10000, 12500, 13125};
    const int HW[4] = {100, 50, 25, 13};
    const float* offp = offaw + (size_t)bq * 384 + h * 32;

    // softmax over 16 logits (replicated across the four 16-lane groups)
    float myl = offaw[(size_t)bq * 384 + 256 + h * 16 + (lane & 15)];
    float mxl = myl;
#pragma unroll
    for (int o = 1; o < 16; o <<= 1) mxl = fmaxf(mxl, __shfl_xor(mxl, o));
    float e = expf(myl - mxl), se = e;
#pragma unroll
    for (int o = 1; o < 16; o <<= 1) se += __shfl_xor(se, o);
    const float myaw = e / se;

    f32x4 acc = {};
    float wsum = 0.f;
    const float* mb = memory + (size_t)b * LEN_ * 256 + lane * 4;
#pragma unroll
    for (int l = 0; l < NL_; ++l) {
        const int Hl = HW[l], Wl = HW[l], st = starts[l];
        const float rx = refp[(bq * NL_ + l) * 2 + 0];
        const float ry = refp[(bq * NL_ + l) * 2 + 1];
#pragma unroll
        for (int p = 0; p < NP_; ++p) {
            const float ox = offp[l * 8 + p * 2 + 0];
            const float oy = offp[l * 8 + p * 2 + 1];
            const float x = (rx + ox / (float)Wl) * (float)Wl - 0.5f;
            const float y = (ry + oy / (float)Hl) * (float)Hl - 0.5f;
            const float x0 = floorf(x), y0 = floorf(y);
            const float dx = x - x0, dy = y - y0;
            const int ix0 = (int)x0, iy0 = (int)y0;
            const float aw = __shfl(myaw, l * 4 + p, 16);
#pragma unroll
            for (int cor = 0; cor < 4; ++cor) {
                const int xi = ix0 + (cor & 1), yi = iy0 + (cor >> 1);
                if (xi >= 0 && xi < Wl && yi >= 0 && yi < Hl) {
                    const float wg = aw * (cor & 1 ? dx : 1.f - dx) * (cor >> 1 ? dy : 1.f - dy);
                    const f32x4 v = *(const f32x4*)(mb + (size_t)(st + yi * Wl + xi) * 256);
                    acc += wg * v;
                    wsum += wg;
                }
            }
        }
    }
    *(f32x4*)(agg + (size_t)g * 256 + lane * 4) = acc;
    if (lane == 0) wsumb[g] = wsum;
}

// ---------------- deferred value projection: dsout = agg @ Wval_h + wsum*b_h ----------------
// One wave per (16 bq rows, head h): A = agg rows (fp32->bf16 in-reg), B = Wval_t slice.
__global__ __launch_bounds__(256) void k_proj(const float* __restrict__ agg,
                                              const float* __restrict__ wsumb,
                                              const bf16* __restrict__ Wval_t,
                                              const float* __restrict__ b_val,
                                              bf16* __restrict__ dsout) {
    const int w = threadIdx.x >> 6, lane = threadIdx.x & 63;
    const int gw = blockIdx.x * 4 + w;       // 0..1199
    const int h = gw & 7, r0 = (gw >> 3) * 16;
    const int fr = lane & 15, fq = lane >> 4;
    const float* arow = agg + (size_t)((r0 + fr) * 8 + h) * 256 + fq * 8;
    const bf16*  bb   = Wval_t + (size_t)(h * 32 + fr) * 256 + fq * 8;
    f32x4 acc[2] = {};
#pragma unroll
    for (int it = 0; it < 8; ++it) {
        const f32x4* ap = (const f32x4*)(arow + it * 32);
        f32x4 a0 = ap[0], a1 = ap[1];
        union { short s[8]; bf16x8 v; } cv;
        cv.s[0] = f2bfbits(a0[0]); cv.s[1] = f2bfbits(a0[1]);
        cv.s[2] = f2bfbits(a0[2]); cv.s[3] = f2bfbits(a0[3]);
        cv.s[4] = f2bfbits(a1[0]); cv.s[5] = f2bfbits(a1[1]);
        cv.s[6] = f2bfbits(a1[2]); cv.s[7] = f2bfbits(a1[3]);
        bf16x8 af = cv.v;
#pragma unroll
        for (int n = 0; n < 2; ++n) {
            bf16x8 bf8 = *(const bf16x8*)(bb + (size_t)n * 16 * 256 + it * 32);
            acc[n] = __builtin_amdgcn_mfma_f32_16x16x32_bf16(af, bf8, acc[n], 0, 0, 0);
        }
    }
#pragma unroll
    for (int n = 0; n < 2; ++n) {
        const int c = h * 32 + n * 16 + fr;
        const float bias = b_val[c];
#pragma unroll
        for (int j = 0; j < 4; ++j) {
            const int row = r0 + fq * 4 + j;
            dsout[(size_t)row * 256 + c] =
                __float2bfloat16(acc[n][j] + wsumb[row * 8 + h] * bias);
        }
    }
}

// ---------------- launch ----------------
extern "C" void kernel_launch(void* const* d_in, const int* in_sizes, int n_in,
                              void* d_out, int out_size, void* d_ws, size_t ws_size,
                              hipStream_t stream) {
    const float* tgt    = (const float*)d_in[0];
    const float* refp   = (const float*)d_in[1];
    const float* memory = (const float*)d_in[2];
    const float* qpe    = (const float*)d_in[3];
    const float* Wq     = (const float*)d_in[4];  const float* bq_  = (const float*)d_in[5];
    const float* Wk     = (const float*)d_in[6];  const float* bk_  = (const float*)d_in[7];
    const float* Wv     = (const float*)d_in[8];  const float* bv_  = (const float*)d_in[9];
    const float* Wo     = (const float*)d_in[10]; const float* bo_  = (const float*)d_in[11];
    const float* g1     = (const float*)d_in[12]; const float* be1  = (const float*)d_in[13];
    const float* W_off  = (const float*)d_in[14]; const float* b_off  = (const float*)d_in[15];
    const float* W_attn = (const float*)d_in[16]; const float* b_attn = (const float*)d_in[17];
    const float* W_val  = (const float*)d_in[18]; const float* b_val  = (const float*)d_in[19];
    const float* W_out  = (const float*)d_in[20]; const float* b_out  = (const float*)d_in[21];
    const float* g2     = (const float*)d_in[22]; const float* be2  = (const float*)d_in[23];
    const float* W1     = (const float*)d_in[24]; const float* b1   = (const float*)d_in[25];
    const float* W2     = (const float*)d_in[26]; const float* b2   = (const float*)d_in[27];
    const float* g3     = (const float*)d_in[28]; const float* be3  = (const float*)d_in[29];
    float* out = (float*)d_out;

    // ---- workspace layout ----
    char* base = (char*)d_ws;
    size_t off = 0;
    auto alloc = [&](size_t bytes) -> char* {
        char* p = base + off; off = (off + bytes + 255) & ~(size_t)255; return p;
    };
    float* t1       = (float*)alloc(MQ_ * C_ * 4);
    float* offaw    = (float*)alloc((size_t)MQ_ * 384 * 4);
    bf16*  query_bf = (bf16*) alloc(MQ_ * C_ * 2);
    bf16*  dsout_bf = (bf16*) alloc(MQ_ * C_ * 2);
    bf16*  Wqk_t  = (bf16*)alloc(512 * C_ * 2);     // Wq | Wk transposed
    bf16*  Wv_t   = (bf16*)alloc(C_ * C_ * 2);
    bf16*  Wo_t   = (bf16*)alloc(C_ * C_ * 2);
    bf16*  Wval_t = (bf16*)alloc(C_ * C_ * 2);
    bf16*  Woa_t  = (bf16*)alloc(384 * C_ * 2);     // W_off | W_attn transposed
    bf16*  Wout_t = (bf16*)alloc(C_ * C_ * 2);
    bf16*  W1_t   = (bf16*)alloc(C_ * DFF_ * 2);
    bf16*  W2_t   = (bf16*)alloc(DFF_ * C_ * 2);
    char*  U      = alloc((size_t)MV_ * C_ * 2);    // union region, 54.45 MB
    // phase-1 overlay
    bf16*  qk_bf  = (bf16*)(U);                     // tgt + qpe
    bf16*  tgt_bf = (bf16*)(U + 1228800);
    bf16*  qkbuf  = (bf16*)(U + 2457600);           // [2400][512] q|k
    bf16*  vb     = (bf16*)(U + 4915200);           // [2400][256]
    bf16*  sa_bf  = (bf16*)(U + 6144000);
    float* saO    = (float*)(U + 7372800);
    // phase-2 overlay (deformable): agg 19.66MB + wsumb
    float* agg    = (float*)(U);
    float* wsumb  = (float*)(U + 19660800);
    // phase-3 overlay
    float* ca     = (float*)(U);
    float* t2     = (float*)(U + 2457600);
    bf16*  t2_bf  = (bf16*) (U + 4915200);
    bf16*  ff1_bf = (bf16*) (U + 6144000);
    float* ff2    = (float*)(U + 11059200);

    // ---- prep (2 launches) ----
    k_wtall<<<992, 256, 0, stream>>>(Wq, Wk, Wv, Wo, W_val, W_off, W_attn, W_out, W1, W2,
                                     Wqk_t, Wv_t, Wo_t, Wval_t, Woa_t, Wout_t, W1_t, W2_t);
    k_dualcvt<<<300, 256, 0, stream>>>(tgt, qpe, qk_bf, tgt_bf, MQ_ * C_ / 8);

    // ---- self-attention ----
    k_gmm64<0,1><<<dim3(8, 38), 256, 0, stream>>>(qk_bf,  Wqk_t, bq_, bk_, 256, nullptr, qkbuf, MQ_, 512, C_);
    k_gmm64<0,1><<<dim3(4, 38), 256, 0, stream>>>(tgt_bf, Wv_t,  bv_, bv_, 256, nullptr, vb,    MQ_, 256, C_);
    k_attn<<<dim3(5, 64), 256, 0, stream>>>(qkbuf, vb, sa_bf);
    k_gmm64<0,0><<<dim3(4, 38), 256, 0, stream>>>(sa_bf, Wo_t, bo_, bo_, 256, saO, nullptr, MQ_, 256, C_);
    k_ln<2><<<2400, 256, 0, stream>>>(tgt, saO, qpe, g1, be1, t1, query_bf, MQ_);

    // ---- deformable cross-attention (linearity: sample raw memory, project after) ----
    k_gmm64<0,0><<<dim3(6, 38), 256, 0, stream>>>(query_bf, Woa_t, b_off, b_attn, 256, offaw, nullptr, MQ_, 384, C_);
    k_sampleraw<<<4800, 256, 0, stream>>>(memory, refp, offaw, agg, wsumb);
    k_proj<<<300, 256, 0, stream>>>(agg, wsumb, Wval_t, b_val, dsout_bf);
    k_gmm64<0,0><<<dim3(4, 38), 256, 0, stream>>>(dsout_bf, Wout_t, b_out, b_out, 256, ca, nullptr, MQ_, 256, C_);
    k_ln<1><<<2400, 256, 0, stream>>>(t1, ca, nullptr, g2, be2, t2, t2_bf, MQ_);

    // ---- FFN ----
    k_gmm64<1,1><<<dim3(16, 38), 256, 0, stream>>>(t2_bf, W1_t, b1, b1, DFF_, nullptr, ff1_bf, MQ_, DFF_, C_);
    k_gmm64<0,0><<<dim3(4, 38), 256, 0, stream>>>(ff1_bf, W2_t, b2, b2, 256, ff2, nullptr, MQ_, C_, DFF_);
    k_ln<0><<<2400, 256, 0, stream>>>(t2, ff2, nullptr, g3, be3, out, nullptr, MQ_);
}

// Round 15
// 151.393 us; speedup vs baseline: 1.1720x; 1.1720x over previous
//
#include <hip/hip_runtime.h>
#include <hip/hip_bf16.h>
#include <math.h>

// Problem constants
#define B_   8
#define Q_   300
#define C_   256
#define NH_  8
#define NL_  4
#define NP_  4
#define DFF_ 1024
#define DH_  32
#define LEN_ 13294
#define MQ_  (B_*Q_)    // 2400
#define MV_  (B_*LEN_)  // 106352
#define NSTRIP_ 3324    // ceil(MV/32)

typedef __attribute__((ext_vector_type(4))) float f32x4;
typedef __attribute__((ext_vector_type(8))) short bf16x8;
typedef __hip_bfloat16 bf16;

#define GLOAD16(gp, lp) __builtin_amdgcn_global_load_lds( \
    (const __attribute__((address_space(1))) unsigned int*)(gp), \
    (__attribute__((address_space(3))) unsigned int*)(lp), 16, 0, 0)

// bit-preserving float -> bf16 bits (avoid short->bf16 numeric-conversion trap)
__device__ __forceinline__ short f2bfbits(float x) {
    bf16 h = __float2bfloat16(x);
    return *reinterpret_cast<short*>(&h);
}

// ================= shared device bodies =================

// 64x64 MFMA GEMM tile body (dual bias, runtime RELU/OUT_MODE - epilogue only)
__device__ __forceinline__ void gmm64_body(char* smemraw, int bx, int by,
        const bf16* __restrict__ A, const bf16* __restrict__ Bt,
        const float* __restrict__ bias0, const float* __restrict__ bias1, int nsplit,
        float* __restrict__ outf, bf16* __restrict__ outh,
        int M, int N, int K, int RELU, int OUT_MODE) {
    bf16* As = (bf16*)smemraw;            // 64*32
    bf16* Bs = (bf16*)(smemraw + 4096);   // 64*32
    const int tid  = threadIdx.x;
    const int wid  = tid >> 6, lane = tid & 63;
    const int m0 = by * 64, n0 = bx * 64;
    const int wr = wid >> 1, wc = wid & 1;
    const int fr = lane & 15, fq = lane >> 4;
    const int rloc = wid * 16 + (lane >> 2);
    const int kof  = (lane & 3) * 8;
    f32x4 acc[2][2] = {};
    for (int k0 = 0; k0 < K; k0 += 32) {
        if (k0) __syncthreads();
        int gr = m0 + rloc; if (gr > M - 1) gr = M - 1;
        GLOAD16(A + (size_t)gr * K + k0 + kof, As + rloc * 32);
        int gc = n0 + rloc; if (gc > N - 1) gc = N - 1;
        GLOAD16(Bt + (size_t)gc * K + k0 + kof, Bs + rloc * 32);
        __syncthreads();
        bf16x8 af[2], bfr[2];
#pragma unroll
        for (int m = 0; m < 2; ++m)
            af[m] = *(const bf16x8*)(As + (wr * 32 + m * 16 + fr) * 32 + fq * 8);
#pragma unroll
        for (int n = 0; n < 2; ++n)
            bfr[n] = *(const bf16x8*)(Bs + (wc * 32 + n * 16 + fr) * 32 + fq * 8);
#pragma unroll
        for (int m = 0; m < 2; ++m)
#pragma unroll
            for (int n = 0; n < 2; ++n)
                acc[m][n] = __builtin_amdgcn_mfma_f32_16x16x32_bf16(af[m], bfr[n], acc[m][n], 0, 0, 0);
    }
#pragma unroll
    for (int m = 0; m < 2; ++m) {
#pragma unroll
        for (int n = 0; n < 2; ++n) {
            const int c = n0 + wc * 32 + n * 16 + fr;
            const float bs = (c < nsplit) ? bias0[c] : bias1[c - nsplit];
#pragma unroll
            for (int j = 0; j < 4; ++j) {
                const int r = m0 + wr * 32 + m * 16 + fq * 4 + j;
                if (r >= M) continue;
                float v = acc[m][n][j] + bs;
                if (RELU) v = fmaxf(v, 0.f);
                if (OUT_MODE == 0) outf[(size_t)r * N + c] = v;
                else               outh[(size_t)r * N + c] = __float2bfloat16(v);
            }
        }
    }
}

// value GEMM body: strip-persistent, B-in-registers, 1 barrier/strip (r13-verified)
__device__ __forceinline__ void gmmV_body(char* smemraw, int bid,
        const float* __restrict__ A, const bf16* __restrict__ Bt,
        const float* __restrict__ bias, bf16* __restrict__ outh, int M) {
    short (*As)[8192] = (short(*)[8192])smemraw;   // [2][8*32*32], 16 KB each
    const int tid = threadIdx.x;
    const int w = tid >> 6, lane = tid & 63;
    const int fr = lane & 15, fq = lane >> 4;
    const int r   = tid >> 3;              // staging row 0..31
    const int itc = tid & 7;               // staging k-chunk 0..7

    bf16x8 bc[4][8];
#pragma unroll
    for (int n = 0; n < 4; ++n)
#pragma unroll
        for (int it = 0; it < 8; ++it)
            bc[n][it] = *(const bf16x8*)(Bt + (size_t)(w * 64 + n * 16 + fr) * 256 + it * 32 + fq * 8);
    float bs[4];
#pragma unroll
    for (int n = 0; n < 4; ++n) bs[n] = bias[w * 64 + n * 16 + fr];

    const int sbase = bid * 4;
    float4 pf[8];

#define LOADA(s_) { \
        int row_ = (s_) * 32 + r; if (row_ > M - 1) row_ = M - 1; \
        const float4* p_ = (const float4*)(A + (size_t)row_ * 256 + itc * 32); \
        pf[0] = p_[0]; pf[1] = p_[1]; pf[2] = p_[2]; pf[3] = p_[3]; \
        pf[4] = p_[4]; pf[5] = p_[5]; pf[6] = p_[6]; pf[7] = p_[7]; }
#define WRITEA(buf_) { \
        short* dst_ = &As[buf_][itc * 1024 + r * 32]; \
        _Pragma("unroll") \
        for (int g_ = 0; g_ < 4; ++g_) { \
            float4 a0_ = pf[2 * g_], a1_ = pf[2 * g_ + 1]; \
            union { short h[8]; bf16x8 v; } cv_; \
            cv_.h[0] = f2bfbits(a0_.x); cv_.h[1] = f2bfbits(a0_.y); \
            cv_.h[2] = f2bfbits(a0_.z); cv_.h[3] = f2bfbits(a0_.w); \
            cv_.h[4] = f2bfbits(a1_.x); cv_.h[5] = f2bfbits(a1_.y); \
            cv_.h[6] = f2bfbits(a1_.z); cv_.h[7] = f2bfbits(a1_.w); \
            *(bf16x8*)(dst_ + g_ * 8) = cv_.v; \
        } }

    LOADA(sbase);
    WRITEA(0);
    __syncthreads();
    int buf = 0;
#pragma unroll 1
    for (int i = 0; i < 4; ++i) {
        const int s = sbase + i;
        if (s >= NSTRIP_) break;
        const bool more = (i < 3) && (s + 1 < NSTRIP_);
        if (more) LOADA(s + 1);
        f32x4 acc[2][4] = {};
#pragma unroll
        for (int it = 0; it < 8; ++it) {
            bf16x8 af[2];
#pragma unroll
            for (int m = 0; m < 2; ++m)
                af[m] = *(const bf16x8*)&As[buf][it * 1024 + (m * 16 + fr) * 32 + fq * 8];
#pragma unroll
            for (int m = 0; m < 2; ++m)
#pragma unroll
                for (int n = 0; n < 4; ++n)
                    acc[m][n] = __builtin_amdgcn_mfma_f32_16x16x32_bf16(af[m], bc[n][it], acc[m][n], 0, 0, 0);
        }
        if (more) WRITEA(buf ^ 1);
#pragma unroll
        for (int m = 0; m < 2; ++m)
#pragma unroll
            for (int n = 0; n < 4; ++n) {
                const int c = w * 64 + n * 16 + fr;
#pragma unroll
                for (int j = 0; j < 4; ++j) {
                    const int row = s * 32 + m * 16 + fq * 4 + j;
                    if (row < M)
                        outh[(size_t)row * 256 + c] = __float2bfloat16(acc[m][n][j] + bs[n]);
                }
            }
        if (more) __syncthreads();
        buf ^= 1;
    }
#undef LOADA
#undef WRITEA
}

// ================= kernels =================

// prep: weight transposes (blocks 0..991) + dual convert (blocks 992..1291)
__global__ __launch_bounds__(256) void k_prep(
        const float* __restrict__ Wq, const float* __restrict__ Wk,
        const float* __restrict__ Wv, const float* __restrict__ Wo,
        const float* __restrict__ Wval, const float* __restrict__ Woff,
        const float* __restrict__ Wattn, const float* __restrict__ Wout,
        const float* __restrict__ W1, const float* __restrict__ W2,
        bf16* __restrict__ Wqk_t, bf16* __restrict__ Wv_t, bf16* __restrict__ Wo_t,
        bf16* __restrict__ Wval_t, bf16* __restrict__ Woa_t, bf16* __restrict__ Wout_t,
        bf16* __restrict__ W1_t, bf16* __restrict__ W2_t,
        const float* __restrict__ tgt, const float* __restrict__ qpe,
        bf16* __restrict__ qk_o, bf16* __restrict__ tgt_o) {
    __shared__ float t[32][33];
    const int id = blockIdx.x;
    if (id < 992) {
        const float* W; bf16* D; int K, N, r;
        if      (id < 64)  { W = Wq;    D = Wqk_t;          K = 256;  N = 256;  r = id; }
        else if (id < 128) { W = Wk;    D = Wqk_t + 65536;  K = 256;  N = 256;  r = id - 64; }
        else if (id < 192) { W = Wv;    D = Wv_t;           K = 256;  N = 256;  r = id - 128; }
        else if (id < 256) { W = Wo;    D = Wo_t;           K = 256;  N = 256;  r = id - 192; }
        else if (id < 320) { W = Wval;  D = Wval_t;         K = 256;  N = 256;  r = id - 256; }
        else if (id < 384) { W = Woff;  D = Woa_t;          K = 256;  N = 256;  r = id - 320; }
        else if (id < 416) { W = Wattn; D = Woa_t + 65536;  K = 256;  N = 128;  r = id - 384; }
        else if (id < 480) { W = Wout;  D = Wout_t;         K = 256;  N = 256;  r = id - 416; }
        else if (id < 736) { W = W1;    D = W1_t;           K = 256;  N = 1024; r = id - 480; }
        else               { W = W2;    D = W2_t;           K = 1024; N = 256;  r = id - 736; }
        const int nx = N >> 5;
        const int k0 = (r / nx) * 32, n0 = (r % nx) * 32;
        const int c = threadIdx.x & 31, rr = threadIdx.x >> 5;
#pragma unroll
        for (int i = 0; i < 4; ++i)
            t[rr + i * 8][c] = W[(size_t)(k0 + rr + i * 8) * N + n0 + c];
        __syncthreads();
#pragma unroll
        for (int i = 0; i < 4; ++i)
            D[(size_t)(n0 + rr + i * 8) * K + k0 + c] = __float2bfloat16(t[c][rr + i * 8]);
    } else {
        const int i = (id - 992) * 256 + threadIdx.x;
        if (i >= MQ_ * C_ / 8) return;
        const float4* pa = (const float4*)(tgt + (size_t)i * 8);
        const float4* pb = (const float4*)(qpe + (size_t)i * 8);
        float4 x = pa[0], y = pa[1], u = pb[0], w = pb[1];
        union { bf16 h[8]; uint4 v; } s, tt;
        s.h[0] = __float2bfloat16(x.x + u.x); s.h[1] = __float2bfloat16(x.y + u.y);
        s.h[2] = __float2bfloat16(x.z + u.z); s.h[3] = __float2bfloat16(x.w + u.w);
        s.h[4] = __float2bfloat16(y.x + w.x); s.h[5] = __float2bfloat16(y.y + w.y);
        s.h[6] = __float2bfloat16(y.z + w.z); s.h[7] = __float2bfloat16(y.w + w.w);
        tt.h[0] = __float2bfloat16(x.x); tt.h[1] = __float2bfloat16(x.y);
        tt.h[2] = __float2bfloat16(x.z); tt.h[3] = __float2bfloat16(x.w);
        tt.h[4] = __float2bfloat16(y.x); tt.h[5] = __float2bfloat16(y.y);
        tt.h[6] = __float2bfloat16(y.z); tt.h[7] = __float2bfloat16(y.w);
        *(uint4*)(qk_o + (size_t)i * 8)  = s.v;
        *(uint4*)(tgt_o + (size_t)i * 8) = tt.v;
    }
}

// mega: value GEMM (blocks 0..831) || qk-proj (832..1135) || v-proj (1136..1287)
__global__ __launch_bounds__(256, 2) void k_mega(
        const float* __restrict__ memory, const bf16* __restrict__ Wval_t,
        const float* __restrict__ b_val, bf16* __restrict__ value_bf,
        const bf16* __restrict__ qk_bf, const bf16* __restrict__ Wqk_t,
        const float* __restrict__ bq_, const float* __restrict__ bk_, bf16* __restrict__ qkbuf,
        const bf16* __restrict__ tgt_bf, const bf16* __restrict__ Wv_t,
        const float* __restrict__ bv_, bf16* __restrict__ vb) {
    __shared__ char smem[32768];
    const int bid = blockIdx.x;
    if (bid < 832) {
        gmmV_body(smem, bid, memory, Wval_t, b_val, value_bf, MV_);
    } else if (bid < 1136) {
        const int r = bid - 832;
        gmm64_body(smem, r & 7, r >> 3, qk_bf, Wqk_t, bq_, bk_, 256, nullptr, qkbuf, MQ_, 512, C_, 0, 1);
    } else {
        const int r = bid - 1136;
        gmm64_body(smem, r & 3, r >> 2, tgt_bf, Wv_t, bv_, bv_, 256, nullptr, vb, MQ_, 256, C_, 0, 1);
    }
}

// standalone 64x64 GEMM
template<int RELU, int OUT_MODE>
__global__ __launch_bounds__(256) void k_gmm64(const bf16* __restrict__ A,
                                               const bf16* __restrict__ Bt,
                                               const float* __restrict__ bias0,
                                               const float* __restrict__ bias1,
                                               int nsplit,
                                               float* __restrict__ outf,
                                               bf16* __restrict__ outh,
                                               int M, int N, int K) {
    __shared__ char smem[8192];
    gmm64_body(smem, blockIdx.x, blockIdx.y, A, Bt, bias0, bias1, nsplit,
               outf, outh, M, N, K, RELU, OUT_MODE);
}

// ---------------- fused self-attention: QK^T -> softmax -> PV ----------------
__global__ __launch_bounds__(256) void k_attn(const bf16* __restrict__ qk2,
                                              const bf16* __restrict__ vb,
                                              bf16* __restrict__ sa) {
    __shared__ short Ks[304][40];
    __shared__ short Vt[32][328];
    __shared__ short Ps[4][16][168];
    const int tid = threadIdx.x, w = tid >> 6, lane = tid & 63;
    const int fr = lane & 15, fq = lane >> 4;
    const int bh = blockIdx.y, b = bh >> 3, h = bh & 7;
    const int qbase = blockIdx.x * 64;

    for (int k0 = 0; k0 < 300; k0 += 64) {
        int key = k0 + (tid >> 2);
        int dc = (tid & 3) * 8;
        if (key < 300) {
            *(bf16x8*)&Ks[key][dc] =
                *(const bf16x8*)&qk2[((size_t)(b * 300 + key)) * 512 + 256 + h * 32 + dc];
            bf16x8 v8 = *(const bf16x8*)&vb[((size_t)(b * 300 + key)) * 256 + h * 32 + dc];
#pragma unroll
            for (int i = 0; i < 8; ++i) Vt[dc + i][key] = v8[i];
        }
    }
    for (int i = tid; i < 32 * 20; i += 256) Vt[i & 31][300 + (i >> 5)] = 0;

    int qrow = qbase + w * 16 + fr;
    int qr = qrow < 300 ? qrow : 299;
    bf16x8 qf = *(const bf16x8*)&qk2[((size_t)(b * 300 + qr)) * 512 + h * 32 + fq * 8];
    __syncthreads();

    f32x4 s[19];
#pragma unroll
    for (int kf = 0; kf < 19; ++kf) {
        bf16x8 kfr = *(const bf16x8*)&Ks[kf * 16 + fr][fq * 8];
        f32x4 z = {};
        s[kf] = __builtin_amdgcn_mfma_f32_16x16x32_bf16(qf, kfr, z, 0, 0, 0);
    }
    const float scale = 0.17677669529663687f;
#pragma unroll
    for (int kf = 0; kf < 19; ++kf)
#pragma unroll
        for (int j = 0; j < 4; ++j) s[kf][j] *= scale;
    if (288 + fr >= 300) {
#pragma unroll
        for (int j = 0; j < 4; ++j) s[18][j] = -1e30f;
    }
    float mx[4], sm[4], inv[4];
#pragma unroll
    for (int j = 0; j < 4; ++j) {
        mx[j] = s[0][j];
#pragma unroll
        for (int kf = 1; kf < 19; ++kf) mx[j] = fmaxf(mx[j], s[kf][j]);
    }
#pragma unroll
    for (int off = 1; off < 16; off <<= 1)
#pragma unroll
        for (int j = 0; j < 4; ++j) mx[j] = fmaxf(mx[j], __shfl_xor(mx[j], off));
#pragma unroll
    for (int j = 0; j < 4; ++j) sm[j] = 0.f;
#pragma unroll
    for (int kf = 0; kf < 19; ++kf)
#pragma unroll
        for (int j = 0; j < 4; ++j) { s[kf][j] = expf(s[kf][j] - mx[j]); sm[j] += s[kf][j]; }
#pragma unroll
    for (int off = 1; off < 16; off <<= 1)
#pragma unroll
        for (int j = 0; j < 4; ++j) sm[j] += __shfl_xor(sm[j], off);
#pragma unroll
    for (int j = 0; j < 4; ++j) inv[j] = 1.f / sm[j];

    f32x4 o[2] = {};
#pragma unroll
    for (int half = 0; half < 2; ++half) {
        const int kfbeg = half * 10, kfend = half ? 19 : 10;
#pragma unroll
        for (int kf = kfbeg; kf < kfend; ++kf) {
            int gcol = kf * 16 + fr, lcol = gcol - half * 160;
            bool valid = gcol < 300;
#pragma unroll
            for (int j = 0; j < 4; ++j)
                Ps[w][fq * 4 + j][lcol] = valid ? f2bfbits(s[kf][j] * inv[j]) : (short)0;
        }
        if (half) {
            int r = lane >> 2, c0 = 144 + (lane & 3) * 4;
#pragma unroll
            for (int i = 0; i < 4; ++i) Ps[w][r][c0 + i] = 0;
        }
#pragma unroll
        for (int ks = 0; ks < 5; ++ks) {
            bf16x8 pa = *(const bf16x8*)&Ps[w][fr][ks * 32 + fq * 8];
#pragma unroll
            for (int n = 0; n < 2; ++n) {
                bf16x8 vf = *(const bf16x8*)&Vt[n * 16 + fr][half * 160 + ks * 32 + fq * 8];
                o[n] = __builtin_amdgcn_mfma_f32_16x16x32_bf16(pa, vf, o[n], 0, 0, 0);
            }
        }
    }
#pragma unroll
    for (int n = 0; n < 2; ++n)
#pragma unroll
        for (int j = 0; j < 4; ++j) {
            int row = qbase + w * 16 + fq * 4 + j;
            if (row < 300)
                sa[((size_t)(b * 300 + row)) * 256 + h * 32 + n * 16 + fr] = __float2bfloat16(o[n][j]);
        }
}

// ---------------- LayerNorm(x + res); WB=1: outh=bf16(y); WB=2: outh=bf16(y+qpe) ----------------
template<int WB>
__global__ __launch_bounds__(256) void k_ln(const float* __restrict__ x,
                                            const float* __restrict__ res,
                                            const float* __restrict__ qpe,
                                            const float* __restrict__ g,
                                            const float* __restrict__ be,
                                            float* __restrict__ out,
                                            bf16* __restrict__ outh, int rows) {
    const int row = blockIdx.x;
    const int tid = threadIdx.x;
    float v = x[row * C_ + tid] + res[row * C_ + tid];
    __shared__ float red[4];
    float s = v;
#pragma unroll
    for (int off = 32; off; off >>= 1) s += __shfl_xor(s, off);
    if ((tid & 63) == 0) red[tid >> 6] = s;
    __syncthreads();
    float mean = (red[0] + red[1] + red[2] + red[3]) * (1.f / C_);
    float dv = v - mean;
    float s2 = dv * dv;
    __syncthreads();
#pragma unroll
    for (int off = 32; off; off >>= 1) s2 += __shfl_xor(s2, off);
    if ((tid & 63) == 0) red[tid >> 6] = s2;
    __syncthreads();
    float var = (red[0] + red[1] + red[2] + red[3]) * (1.f / C_);
    float rstd = 1.f / sqrtf(var + 1e-5f);
    float y = dv * rstd * g[tid] + be[tid];
    out[row * C_ + tid] = y;
    if (WB == 1) outh[row * C_ + tid] = __float2bfloat16(y);
    if (WB == 2) outh[row * C_ + tid] = __float2bfloat16(y + qpe[row * C_ + tid]);
}

// ---------------- deformable bilinear sampling + fused aw-softmax (bf16 value) ----------------
__global__ __launch_bounds__(256) void k_sample(const bf16* __restrict__ value,
                                                const float* __restrict__ refp,
                                                const float* __restrict__ offaw,
                                                bf16* __restrict__ out) {
    const int t  = blockIdx.x * 256 + threadIdx.x;
    const int d2 = t & 15;
    const int g  = t >> 4;
    const int h  = g & 7;
    const int bq = g >> 3;
    const int b  = bq / Q_;
    const int starts[4] = {0, 10000, 12500, 13125};
    const int HW[4]     = {100, 50, 25, 13};
    const float* offp = offaw + (size_t)bq * 384 + h * 32;

    float myl = offaw[(size_t)bq * 384 + 256 + h * 16 + d2];
    float mxl = myl;
#pragma unroll
    for (int o = 1; o < 16; o <<= 1) mxl = fmaxf(mxl, __shfl_xor(mxl, o));
    float e = expf(myl - mxl);
    float se = e;
#pragma unroll
    for (int o = 1; o < 16; o <<= 1) se += __shfl_xor(se, o);
    const float myaw = e / se;

    float acc0 = 0.f, acc1 = 0.f;
#pragma unroll
    for (int l = 0; l < NL_; ++l) {
        const int Hl = HW[l], Wl = HW[l], st = starts[l];
        const float rx = refp[(bq * NL_ + l) * 2 + 0];
        const float ry = refp[(bq * NL_ + l) * 2 + 1];
        const bf16* vbase = value + ((size_t)b * LEN_ + st) * C_ + h * DH_ + d2 * 2;
#pragma unroll
        for (int p = 0; p < NP_; ++p) {
            const float ox = offp[l * 8 + p * 2 + 0];
            const float oy = offp[l * 8 + p * 2 + 1];
            const float x = (rx + ox / (float)Wl) * (float)Wl - 0.5f;
            const float y = (ry + oy / (float)Hl) * (float)Hl - 0.5f;
            const float x0 = floorf(x), y0 = floorf(y);
            const float dx = x - x0, dy = y - y0;
            const int ix0 = (int)x0, iy0 = (int)y0;
            const float aw = __shfl(myaw, l * 4 + p, 16);
            float s0 = 0.f, s1 = 0.f;
#pragma unroll
            for (int cor = 0; cor < 4; ++cor) {
                const int xi = ix0 + (cor & 1), yi = iy0 + (cor >> 1);
                if (xi >= 0 && xi < Wl && yi >= 0 && yi < Hl) {
                    const float wg = (cor & 1 ? dx : 1.f - dx) * (cor >> 1 ? dy : 1.f - dy);
                    const unsigned u = *(const unsigned*)(vbase + (size_t)(yi * Wl + xi) * C_);
                    bf16 lo, hi;
                    *reinterpret_cast<short*>(&lo) = (short)(u & 0xFFFF);
                    *reinterpret_cast<short*>(&hi) = (short)(u >> 16);
                    s0 += wg * __bfloat162float(lo);
                    s1 += wg * __bfloat162float(hi);
                }
            }
            acc0 += aw * s0;
            acc1 += aw * s1;
        }
    }
    union { short h2[2]; unsigned u; } pack;
    pack.h2[0] = f2bfbits(acc0);
    pack.h2[1] = f2bfbits(acc1);
    *(unsigned*)(out + (size_t)bq * C_ + h * DH_ + d2 * 2) = pack.u;
}

// ---------------- launch ----------------
extern "C" void kernel_launch(void* const* d_in, const int* in_sizes, int n_in,
                              void* d_out, int out_size, void* d_ws, size_t ws_size,
                              hipStream_t stream) {
    const float* tgt    = (const float*)d_in[0];
    const float* refp   = (const float*)d_in[1];
    const float* memory = (const float*)d_in[2];
    const float* qpe    = (const float*)d_in[3];
    const float* Wq     = (const float*)d_in[4];  const float* bq_  = (const float*)d_in[5];
    const float* Wk     = (const float*)d_in[6];  const float* bk_  = (const float*)d_in[7];
    const float* Wv     = (const float*)d_in[8];  const float* bv_  = (const float*)d_in[9];
    const float* Wo     = (const float*)d_in[10]; const float* bo_  = (const float*)d_in[11];
    const float* g1     = (const float*)d_in[12]; const float* be1  = (const float*)d_in[13];
    const float* W_off  = (const float*)d_in[14]; const float* b_off  = (const float*)d_in[15];
    const float* W_attn = (const float*)d_in[16]; const float* b_attn = (const float*)d_in[17];
    const float* W_val  = (const float*)d_in[18]; const float* b_val  = (const float*)d_in[19];
    const float* W_out  = (const float*)d_in[20]; const float* b_out  = (const float*)d_in[21];
    const float* g2     = (const float*)d_in[22]; const float* be2  = (const float*)d_in[23];
    const float* W1     = (const float*)d_in[24]; const float* b1   = (const float*)d_in[25];
    const float* W2     = (const float*)d_in[26]; const float* b2   = (const float*)d_in[27];
    const float* g3     = (const float*)d_in[28]; const float* be3  = (const float*)d_in[29];
    float* out = (float*)d_out;

    // ---- workspace layout ----
    char* base = (char*)d_ws;
    size_t off = 0;
    auto alloc = [&](size_t bytes) -> char* {
        char* p = base + off; off = (off + bytes + 255) & ~(size_t)255; return p;
    };
    float* t1       = (float*)alloc(MQ_ * C_ * 4);
    float* offaw    = (float*)alloc((size_t)MQ_ * 384 * 4);
    bf16*  query_bf = (bf16*) alloc(MQ_ * C_ * 2);
    bf16*  dsout_bf = (bf16*) alloc(MQ_ * C_ * 2);
    bf16*  Wqk_t  = (bf16*)alloc(512 * C_ * 2);     // Wq | Wk transposed
    bf16*  Wv_t   = (bf16*)alloc(C_ * C_ * 2);
    bf16*  Wo_t   = (bf16*)alloc(C_ * C_ * 2);
    bf16*  Wval_t = (bf16*)alloc(C_ * C_ * 2);
    bf16*  Woa_t  = (bf16*)alloc(384 * C_ * 2);     // W_off | W_attn transposed
    bf16*  Wout_t = (bf16*)alloc(C_ * C_ * 2);
    bf16*  W1_t   = (bf16*)alloc(C_ * DFF_ * 2);
    bf16*  W2_t   = (bf16*)alloc(DFF_ * C_ * 2);
    bf16*  value_bf = (bf16*)alloc((size_t)MV_ * C_ * 2);  // own region (mega overlap!)
    char*  U      = alloc((size_t)MV_ * C_ * 2);           // phase-1/3 overlay region
    // phase-1 overlay
    bf16*  qk_bf  = (bf16*)(U);                     // tgt + qpe
    bf16*  tgt_bf = (bf16*)(U + 1228800);
    bf16*  qkbuf  = (bf16*)(U + 2457600);           // [2400][512] q|k
    bf16*  vb     = (bf16*)(U + 4915200);           // [2400][256]
    bf16*  sa_bf  = (bf16*)(U + 6144000);
    float* saO    = (float*)(U + 7372800);
    // phase-3 overlay
    float* ca     = (float*)(U);
    float* t2     = (float*)(U + 2457600);
    bf16*  t2_bf  = (bf16*) (U + 4915200);
    bf16*  ff1_bf = (bf16*) (U + 6144000);
    float* ff2    = (float*)(U + 11059200);

    // 1) prep: weight transposes + input converts
    k_prep<<<1292, 256, 0, stream>>>(Wq, Wk, Wv, Wo, W_val, W_off, W_attn, W_out, W1, W2,
                                     Wqk_t, Wv_t, Wo_t, Wval_t, Woa_t, Wout_t, W1_t, W2_t,
                                     tgt, qpe, qk_bf, tgt_bf);
    // 2) mega: value GEMM || qk-proj || v-proj (independent; gmmV blocks first)
    k_mega<<<1288, 256, 0, stream>>>(memory, Wval_t, b_val, value_bf,
                                     qk_bf, Wqk_t, bq_, bk_, qkbuf,
                                     tgt_bf, Wv_t, bv_, vb);
    // 3) self-attention chain
    k_attn<<<dim3(5, 64), 256, 0, stream>>>(qkbuf, vb, sa_bf);
    k_gmm64<0,0><<<dim3(4, 38), 256, 0, stream>>>(sa_bf, Wo_t, bo_, bo_, 256, saO, nullptr, MQ_, 256, C_);
    k_ln<2><<<2400, 256, 0, stream>>>(tgt, saO, qpe, g1, be1, t1, query_bf, MQ_);
    // 4) deformable cross-attention
    k_gmm64<0,0><<<dim3(6, 38), 256, 0, stream>>>(query_bf, Woa_t, b_off, b_attn, 256, offaw, nullptr, MQ_, 384, C_);
    k_sample<<<1200, 256, 0, stream>>>(value_bf, refp, offaw, dsout_bf);
    k_gmm64<0,0><<<dim3(4, 38), 256, 0, stream>>>(dsout_bf, Wout_t, b_out, b_out, 256, ca, nullptr, MQ_, 256, C_);
    k_ln<1><<<2400, 256, 0, stream>>>(t1, ca, nullptr, g2, be2, t2, t2_bf, MQ_);
    // 5) FFN
    k_gmm64<1,1><<<dim3(16, 38), 256, 0, stream>>>(t2_bf, W1_t, b1, b1, DFF_, nullptr, ff1_bf, MQ_, DFF_, C_);
    k_gmm64<0,0><<<dim3(4, 38), 256, 0, stream>>>(ff1_bf, W2_t, b2, b2, 256, ff2, nullptr, MQ_, C_, DFF_);
    k_ln<0><<<2400, 256, 0, stream>>>(t2, ff2, nullptr, g3, be3, out, nullptr, MQ_);
}